// Round 9
// baseline (283.604 us; speedup 1.0000x reference)
//
#include <hip/hip_runtime.h>
#include <math.h>

#define N 16384
#define NWORDS 256       // N/64
#define FEAT 512
#define NUM_CATS 65
#define K 25
#define MAX_DETS 1000

// ---------------- ws layout (bytes) ----------------
// ckeys    : u64[N]            @ 0         (131072)  compacted candidate keys
// rank     : u32[N]            @ 131072    (65536)
// sbox     : float4[N]         @ 262144    (262144)
// sarea    : f32[N]            @ 524288    (65536)
// mask     : u64[N*NWORDS]     @ 589824    (33554432)
// idxArr   : i32[32]           @ 34144256  (128)   [30]=ticket/ncand
// keepw    : u64[256]          @ 34144384  (2048)  NMS keep bits (sorted pos)
// validw   : u64[256]          @ 34146432  (2048)  valid bits (orig idx order)
// scoresW  : f32[25*65]        @ 34148480  (6500)  classification scores
//
// ROUND 9: round 8 proved the pipeline split (272 us, k_scan=70 standalone).
// The serial greedy chain (~1000 dependent links) is the last serial cost;
// replace it with round 7's CORRECTNESS-PROVEN parallel Jacobi fixpoint
// (passed absmax=0 inside k_tail): K' = init & ~(OR of mask rows of kept
// preds). Greedy keep bits are its unique fixed point; the stabilized prefix
// grows every sweep (guaranteed termination, ~3-6 sweeps here). MAX_DETS
// applied post-hoc (exact: capped greedy == uncapped truncated to first 1000
// kept). 8 waves gather independent mask words -> ~3-4 memory round trips
// per sweep instead of one per kept item.

// Compact candidate keys via ballot + atomic ticket; init rank[] = 0.
__global__ void k_build(const float* __restrict__ scores,
                        unsigned long long* __restrict__ ckeys,
                        unsigned int* __restrict__ rank,
                        int* __restrict__ ticket) {
    int i = blockIdx.x * 256 + threadIdx.x;
    float s = scores[i];
    rank[i] = 0u;                          // safe default for non-candidates
    bool cand = s >= 0.9f;
    unsigned long long bal = __ballot(cand);
    int lane = threadIdx.x & 63;
    int base = 0;
    if (lane == 0) base = atomicAdd(ticket, (int)__popcll(bal));
    base = __shfl(base, 0, 64);
    if (cand) {
        int pre = (int)__popcll(bal & ((1ull << lane) - 1ull));
        ckeys[base + pre] =
            ((unsigned long long)__float_as_uint(s) << 32) |
            (unsigned long long)(0xFFFFFFFFu - (unsigned)i);
    }
}

// Rank candidates among candidates (descending key, distinct keys) and
// scatter boxes/areas into sorted order; write rank[origIdx].
__global__ void k_crank(const unsigned long long* __restrict__ ckeys,
                        const int* __restrict__ ticket,
                        const float* __restrict__ det_boxes,
                        unsigned int* __restrict__ rank,
                        float4* __restrict__ sbox,
                        float* __restrict__ sarea) {
    int nc = *ticket;
    if (nc < 0) nc = 0;
    if (nc > N) nc = N;
    if (blockIdx.x * 256 >= nc) return;    // whole block exits together
    __shared__ unsigned long long lk[2048];
    int ci = blockIdx.x * 256 + threadIdx.x;   // candidate slot this thread ranks
    unsigned long long my = (ci < nc) ? ckeys[ci] : 0ull;
    unsigned int cnt = 0;
    for (int j0 = 0; j0 < nc; j0 += 2048) {
        int m = nc - j0; if (m > 2048) m = 2048;
        __syncthreads();
        for (int t2 = threadIdx.x; t2 < m; t2 += 256) lk[t2] = ckeys[j0 + t2];
        __syncthreads();
        if (ci < nc) {
#pragma unroll 8
            for (int t2 = 0; t2 < m; ++t2) cnt += (lk[t2] > my) ? 1u : 0u;
        }
    }
    if (ci < nc) {
        unsigned int o = 0xFFFFFFFFu - (unsigned int)my;   // original index
        rank[o] = cnt;                                     // global sorted pos
        float4 b = ((const float4*)det_boxes)[o];          // [y1,x1,y2,x2]
        sbox[cnt] = b;
        sarea[cnt] = (b.w - b.y) * (b.z - b.x);            // (x2-x1)*(y2-y1)
    }
}

// Upper-triangular (block-wise) IoU>0.6 bit matrix, candidate chunks only.
// Persistent-tile kernel, fixed 1024-block grid.
__global__ void k_mask(const float4* __restrict__ sbox,
                       const float* __restrict__ sarea,
                       const int* __restrict__ ticket,
                       unsigned long long* __restrict__ mask) {
    int ncand = *ticket;
    if (ncand < 0) ncand = 0;
    if (ncand > N) ncand = N;
    int NC = (ncand + 63) >> 6;
    int total = NC * (NC + 1) / 2;
    __shared__ float4 cbox[64];
    __shared__ float carea[64];
    int t = threadIdx.x;
    for (int tile = blockIdx.x; tile < total; tile += gridDim.x) {
        int cb = (int)((sqrtf(8.0f * (float)tile + 1.0f) - 1.0f) * 0.5f);
        while ((cb + 1) * (cb + 2) / 2 <= tile) ++cb;
        while (cb * (cb + 1) / 2 > tile) --cb;
        int rb = tile - cb * (cb + 1) / 2;

        __syncthreads();                       // protect cbox reuse
        int col0 = cb * 64;
        cbox[t] = sbox[col0 + t];
        carea[t] = sarea[col0 + t];
        __syncthreads();
        int row = rb * 64 + t;
        float4 r = sbox[row];
        float ra = sarea[row];
        unsigned long long bits = 0ull;
        for (int j = 0; j < 64; ++j) {
            int col = col0 + j;
            if (col > row) {
                float4 cbx = cbox[j];
                float iw = fminf(r.w, cbx.w) - fmaxf(r.y, cbx.y);  // x overlap
                iw = fmaxf(iw, 0.0f);
                float ih = fminf(r.z, cbx.z) - fmaxf(r.x, cbx.x);  // y overlap
                ih = fmaxf(ih, 0.0f);
                float inter = iw * ih;
                float iou = inter / (ra + carea[j] - inter + 1e-12f);
                if (iou > 0.6f) bits |= (1ull << j);
            }
        }
        mask[(size_t)row * NWORDS + cb] = bits;
    }
}

// Parallel fixpoint NMS (8 waves). Round-7-proven structure, standalone.
__global__ void __launch_bounds__(512, 1)
k_scanp(const unsigned long long* __restrict__ mask,
        const int* __restrict__ ticket,
        unsigned long long* __restrict__ keepw_ws) {
    __shared__ unsigned long long kw[2][NWORDS];       // Jacobi parity
    __shared__ int keptList[2048];
    __shared__ int nkL, changedL;
    int tid = threadIdx.x;
    int wave = tid >> 6, lane = tid & 63;

    for (int c = tid; c < NWORDS; c += 512) { kw[0][c] = 0ull; kw[1][c] = 0ull; }
    if (tid == 0) { nkL = 0; changedL = 1; }

    int ncand = *ticket;
    if (ncand < 0) ncand = 0;
    if (ncand > N) ncand = N;
    int NC = (ncand + 63) >> 6;
    __syncthreads();

    int par = 0;                       // kw[par] = current K; keptList matches
    for (int sweep = 0; sweep < 20000; ++sweep) {
        int nk = nkL;
        for (int c = wave; c < NC; c += 8) {
            int rem = ncand - c * 64;
            unsigned long long initk = (rem >= 64) ? ~0ull : ((1ull << rem) - 1ull);
            int lim = (c + 1) * 64;
            unsigned long long acc = 0ull;
            int q = lane;
            while (q < nk) {
                unsigned long long G0 = 0, G1 = 0, G2 = 0, G3 = 0;
                int q0 = q, q1 = q + 64, q2 = q + 128, q3 = q + 192;
                if (q0 < nk) { int ps = keptList[q0]; if (ps < lim) G0 = mask[(size_t)ps * NWORDS + c]; }
                if (q1 < nk) { int ps = keptList[q1]; if (ps < lim) G1 = mask[(size_t)ps * NWORDS + c]; }
                if (q2 < nk) { int ps = keptList[q2]; if (ps < lim) G2 = mask[(size_t)ps * NWORDS + c]; }
                if (q3 < nk) { int ps = keptList[q3]; if (ps < lim) G3 = mask[(size_t)ps * NWORDS + c]; }
                acc |= G0 | G1 | G2 | G3;
                q += 256;
            }
            unsigned int alo = (unsigned int)acc;
            unsigned int ahi = (unsigned int)(acc >> 32);
            for (int off = 32; off > 0; off >>= 1) {
                alo |= (unsigned int)__shfl_xor((int)alo, off, 64);
                ahi |= (unsigned int)__shfl_xor((int)ahi, off, 64);
            }
            unsigned long long S = ((unsigned long long)ahi << 32) | alo;
            if (lane == 0) kw[par ^ 1][c] = initk & ~S;
        }
        __syncthreads();

        // wave 0: rebuild keptList from kw[par^1]; detect change
        if (wave == 0) {
            int changed = 0;
            int base = 0;
            for (int g = 0; g * 64 < NC; ++g) {
                int c = g * 64 + lane;
                unsigned long long w = (c < NC) ? kw[par ^ 1][c] : 0ull;
                if (c < NC && w != kw[par][c]) changed = 1;
                int pc = (int)__popcll(w);
                int pref = pc;                         // inclusive prefix
                for (int off = 1; off < 64; off <<= 1) {
                    int v = __shfl_up(pref, off, 64);
                    if (lane >= off) pref += v;
                }
                int excl = base + pref - pc;
                unsigned long long ww = w;
                int k2 = 0;
                while (ww) {
                    int j = __ffsll((long long)ww) - 1;
                    ww &= ww - 1ull;
                    if (excl + k2 < 2048) keptList[excl + k2] = c * 64 + j;
                    ++k2;
                }
                base += __shfl(pref, 63, 64);
            }
            unsigned long long cb = __ballot(changed != 0);
            if (lane == 0) {
                nkL = base < 2048 ? base : 2048;
                changedL = (cb != 0ull) ? 1 : 0;
            }
        }
        __syncthreads();
        par ^= 1;
        if (!changedL) break;          // fixed point == exact greedy
    }

    // MAX_DETS truncation (exact) + zero words >= NC, then write to ws
    if (tid == 0) {
        int cum = 0;
        for (int c = 0; c < NC; ++c) {
            unsigned long long w = kw[par][c];
            int pc = (int)__popcll(w);
            if (cum >= MAX_DETS) kw[par][c] = 0ull;
            else if (cum + pc > MAX_DETS) {
                int allow = MAX_DETS - cum;
                unsigned long long r = 0ull, t2 = w;
                for (int k2 = 0; k2 < allow; ++k2) {
                    unsigned long long b = t2 & (~t2 + 1ull);
                    r |= b; t2 ^= b;
                }
                kw[par][c] = r;
            }
            cum += pc;
        }
        for (int c = NC; c < NWORDS; ++c) kw[par][c] = 0ull;
    }
    __syncthreads();
    for (int c = tid; c < NWORDS; c += 512) keepw_ws[c] = kw[par][c];
}

// Parallel valid bits: 64 blocks x 256. validw[w] bit j = valid(item w*64+j).
__global__ void k_valid(const unsigned long long* __restrict__ keepw_ws,
                        const unsigned int* __restrict__ rank,
                        const float* __restrict__ roi_boxes,
                        const float* __restrict__ roi_scores,
                        const float* __restrict__ det_boxes,
                        const float* __restrict__ info,
                        unsigned long long* __restrict__ validw) {
    int i = blockIdx.x * 256 + threadIdx.x;
    float sy = info[4], sx = info[5];
    unsigned int r = rank[i];
    bool keep = ((keepw_ws[(r >> 6) & (NWORDS - 1)] >> (r & 63)) & 1ull) != 0ull;
    float4 rb = ((const float4*)roi_boxes)[i];
    bool nz = !((rb.x == 0.0f) && (rb.y == 0.0f) && (rb.z == 0.0f) && (rb.w == 0.0f));
    bool sc = roi_scores[i] >= 0.9f;
    float4 db = ((const float4*)det_boxes)[i];
    float r0 = db.x / sy, r1 = db.y / sx, r2 = db.z / sy, r3 = db.w / sx;
    bool big = ((r2 - r0) * (r3 - r1)) > 220.0f;
    bool valid = keep && nz && sc && big;
    unsigned long long bal = __ballot(valid);
    if ((threadIdx.x & 63) == 0) validw[i >> 6] = bal;
}

// First-K pick from the valid bitmask: wave 0 (tids 0..63), lane l owns
// words l*4..l*4+3 (= items [l*256, l*256+256), order-preserving).
__device__ __forceinline__ void pick_first_k(
        const unsigned long long* __restrict__ validw,
        int* idxL, int* cntL, int tid) {
    if (tid < K) idxL[tid] = 0;          // fill_value = 0
    __syncthreads();
    if (tid < 64) {
        int lane = tid;
        unsigned long long w0 = validw[lane * 4 + 0];
        unsigned long long w1 = validw[lane * 4 + 1];
        unsigned long long w2 = validw[lane * 4 + 2];
        unsigned long long w3 = validw[lane * 4 + 3];
        int s = (int)(__popcll(w0) + __popcll(w1) + __popcll(w2) + __popcll(w3));
        int pref = s;                                  // inclusive prefix
        for (int off = 1; off < 64; off <<= 1) {
            int v = __shfl_up(pref, off, 64);
            if (lane >= off) pref += v;
        }
        int excl = pref - s;
        int total = __shfl(pref, 63, 64);
        if (lane == 0) *cntL = total;
        if (excl < K) {
            unsigned long long wsv[4] = { w0, w1, w2, w3 };
            int rk = excl;
            for (int q = 0; q < 4; ++q) {
                unsigned long long ww = wsv[q];
                while (ww && rk < K) {
                    int j = __ffsll((long long)ww) - 1;
                    ww &= ww - 1ull;
                    idxL[rk++] = (lane * 4 + q) * 64 + j;
                }
            }
        }
    }
    __syncthreads();
}

// Classification: one block per detection row. Same sequential accumulation
// order as the previously-passing fused version (absmax == 0 preserved).
__global__ void k_gemm(const unsigned long long* __restrict__ validw,
                       const float* __restrict__ vis,
                       const float* __restrict__ tf,
                       float* __restrict__ scoresW) {
    __shared__ int idxL[K];
    __shared__ int cntL;
    __shared__ float featL[FEAT];
    int tid = threadIdx.x;
    pick_first_k(validw, idxL, &cntL, tid);
    int o = idxL[blockIdx.x];
    if (tid < 128)
        ((float4*)featL)[tid] = ((const float4*)(vis + (size_t)o * FEAT))[tid];
    __syncthreads();
    if (tid < NUM_CATS) {
        const float* tr = &tf[(size_t)tid * FEAT];
        float s = 0.0f;
#pragma unroll 8
        for (int e = 0; e < FEAT; ++e) s += featL[e] * tr[e];
        scoresW[blockIdx.x * NUM_CATS + tid] = s;
    }
}

// Final: argmax/fg, stable descending sort, epilogue writes.
__global__ void k_final(const unsigned long long* __restrict__ validw,
                        const float* __restrict__ scoresW,
                        const float* __restrict__ det_boxes,
                        const float* __restrict__ info,
                        float* __restrict__ out) {
    __shared__ int idxL[K];
    __shared__ int cntL;
    __shared__ float scL[K * NUM_CATS];
    __shared__ float keyL[K];
    __shared__ int fgL[K];
    __shared__ int ordL[K];
    int tid = threadIdx.x;
    pick_first_k(validw, idxL, &cntL, tid);

    for (int p = tid; p < K * NUM_CATS; p += 256) scL[p] = scoresW[p];
    __syncthreads();

    int count = cntL;
    int mincount = count < K ? count : K;

    if (tid < K) {
        float mv = scL[tid * NUM_CATS];
        int ma = 0;
        for (int c = 1; c < NUM_CATS; ++c) {
            float v = scL[tid * NUM_CATS + c];
            if (v > mv) { mv = v; ma = c; }     // first-max (jnp.argmax)
        }
        int fg = (tid < mincount) && (ma != 0);
        fgL[tid] = fg;
        keyL[tid] = fg ? mv : -INFINITY;
    }
    __syncthreads();

    if (tid == 0) {                 // stable selection sort, descending
        unsigned used = 0;
        for (int p = 0; p < K; ++p) {
            int bk = -1; float bv = 0.0f;
            for (int k2 = 0; k2 < K; ++k2) {
                if (used & (1u << k2)) continue;
                if (bk < 0 || keyL[k2] > bv) { bk = k2; bv = keyL[k2]; }
            }
            ordL[p] = bk;
            used |= (1u << bk);
        }
    }
    __syncthreads();

    float sy = info[4], sx = info[5];
    // scores: [0 .. 1599]
    for (int p = tid; p < K * (NUM_CATS - 1); p += 256) {
        int q = p >> 6, cc = p & 63;
        int src = ordL[q];
        out[p] = fgL[src] ? scL[src * NUM_CATS + cc + 1] : 0.0f;
    }
    // bboxes: [1600 .. 1699]  processed = [xmin, ymin, xmax, ymax]
    for (int p = tid; p < K * 4; p += 256) {
        int q = p >> 2, e = p & 3;
        int src = ordL[q];
        float v = 0.0f;
        if (fgL[src]) {
            int o = idxL[src];
            float b0 = det_boxes[o * 4 + 0] / sy;   // ymin
            float b1 = det_boxes[o * 4 + 1] / sx;   // xmin
            float b2 = det_boxes[o * 4 + 2] / sy;   // ymax
            float b3 = det_boxes[o * 4 + 3] / sx;   // xmax
            v = (e == 0) ? b1 : (e == 1) ? b0 : (e == 2) ? b3 : b2;
        }
        out[1600 + p] = v;
    }
    // mask: [1700 .. 1724]
    if (tid < K) out[1700 + tid] = fgL[ordL[tid]] ? 1.0f : 0.0f;
}

extern "C" void kernel_launch(void* const* d_in, const int* in_sizes, int n_in,
                              void* d_out, int out_size, void* d_ws, size_t ws_size,
                              hipStream_t stream) {
    const float* roi_boxes  = (const float*)d_in[0];
    const float* roi_scores = (const float*)d_in[1];
    const float* det_boxes  = (const float*)d_in[2];
    // d_in[3] detection_masks: unused by reference
    const float* vis        = (const float*)d_in[4];
    const float* info       = (const float*)d_in[5];
    const float* tf         = (const float*)d_in[6];

    char* ws = (char*)d_ws;
    unsigned long long* ckeys = (unsigned long long*)(ws + 0);
    unsigned int* rank        = (unsigned int*)(ws + 131072);
    float4* sbox              = (float4*)(ws + 262144);
    float* sarea              = (float*)(ws + 524288);
    unsigned long long* mask  = (unsigned long long*)(ws + 589824);
    int* idxArr               = (int*)(ws + 34144256);
    unsigned long long* keepw = (unsigned long long*)(ws + 34144384);
    unsigned long long* validw= (unsigned long long*)(ws + 34146432);
    float* scoresW            = (float*)(ws + 34148480);
    int* ticket               = idxArr + 30;

    hipMemsetAsync(idxArr, 0, 128, stream);   // zero ticket (graph-capture safe)
    k_build<<<64, 256, 0, stream>>>(roi_scores, ckeys, rank, ticket);
    k_crank<<<64, 256, 0, stream>>>(ckeys, ticket, det_boxes, rank, sbox, sarea);
    k_mask<<<1024, 64, 0, stream>>>(sbox, sarea, ticket, mask);
    k_scanp<<<1, 512, 0, stream>>>(mask, ticket, keepw);
    k_valid<<<64, 256, 0, stream>>>(keepw, rank, roi_boxes, roi_scores,
                                    det_boxes, info, validw);
    k_gemm<<<K, 256, 0, stream>>>(validw, vis, tf, scoresW);
    k_final<<<1, 256, 0, stream>>>(validw, scoresW, det_boxes, info, (float*)d_out);
}

// Round 10
// 231.654 us; speedup vs baseline: 1.2243x; 1.2243x over previous
//
#include <hip/hip_runtime.h>
#include <math.h>

#define N 16384
#define NWORDS 256       // N/64
#define FEAT 512
#define NUM_CATS 65
#define K 25
#define MAX_DETS 1000

// ---------------- ws layout (bytes) ----------------
// ckeys    : u64[N]            @ 0         (131072)  compacted candidate keys
// rank     : u32[N]            @ 131072    (65536)
// sbox     : float4[N]         @ 262144    (262144)
// sarea    : f32[N]            @ 524288    (65536)
// mask     : u64[N*NWORDS]     @ 589824    (33554432)
// idxArr   : i32[32]           @ 34144256  (128)   [30]=ticket/ncand
// keepw    : u64[256]          @ 34144384  (2048)  NMS keep bits (sorted pos)
// validw   : u64[256]          @ 34146432  (2048)  valid bits (orig idx order)
// scoresW  : f32[25*65]        @ 34148480  (6500)  classification scores
//
// ROUND 10: revert to round-8 pipeline (272 us, best) — fixpoint scan
// regressed (85 vs 70: per-sweep rebuild+barriers). k_scan's 70 us is
// ~1030 serial links x ~140cy (readlane VALU->SALU stall + branches).
// ZERO-ROW SHORTCUT: a row whose in-chunk suppression word dcur==0 cannot
// change `alive`, so runs of alive zero-rows between non-zero rows are kept
// WHOLESALE by popcount (cap-checked per segment; the one segment crossing
// MAX_DETS is truncated bit-by-bit, once). Only rows with dcur!=0 (~1 per
// chunk for this data: ~600 edges spread over 1638 cands => ~23 in-chunk
// edges total) pay the serial readlane link. Worst case degrades to the
// old per-item loop.

// Compact candidate keys via ballot + atomic ticket; init rank[] = 0.
__global__ void k_build(const float* __restrict__ scores,
                        unsigned long long* __restrict__ ckeys,
                        unsigned int* __restrict__ rank,
                        int* __restrict__ ticket) {
    int i = blockIdx.x * 256 + threadIdx.x;
    float s = scores[i];
    rank[i] = 0u;                          // safe default for non-candidates
    bool cand = s >= 0.9f;
    unsigned long long bal = __ballot(cand);
    int lane = threadIdx.x & 63;
    int base = 0;
    if (lane == 0) base = atomicAdd(ticket, (int)__popcll(bal));
    base = __shfl(base, 0, 64);
    if (cand) {
        int pre = (int)__popcll(bal & ((1ull << lane) - 1ull));
        ckeys[base + pre] =
            ((unsigned long long)__float_as_uint(s) << 32) |
            (unsigned long long)(0xFFFFFFFFu - (unsigned)i);
    }
}

// Rank candidates among candidates (descending key, distinct keys) and
// scatter boxes/areas into sorted order; write rank[origIdx].
__global__ void k_crank(const unsigned long long* __restrict__ ckeys,
                        const int* __restrict__ ticket,
                        const float* __restrict__ det_boxes,
                        unsigned int* __restrict__ rank,
                        float4* __restrict__ sbox,
                        float* __restrict__ sarea) {
    int nc = *ticket;
    if (nc < 0) nc = 0;
    if (nc > N) nc = N;
    if (blockIdx.x * 256 >= nc) return;    // whole block exits together
    __shared__ unsigned long long lk[2048];
    int ci = blockIdx.x * 256 + threadIdx.x;   // candidate slot this thread ranks
    unsigned long long my = (ci < nc) ? ckeys[ci] : 0ull;
    unsigned int cnt = 0;
    for (int j0 = 0; j0 < nc; j0 += 2048) {
        int m = nc - j0; if (m > 2048) m = 2048;
        __syncthreads();
        for (int t2 = threadIdx.x; t2 < m; t2 += 256) lk[t2] = ckeys[j0 + t2];
        __syncthreads();
        if (ci < nc) {
#pragma unroll 8
            for (int t2 = 0; t2 < m; ++t2) cnt += (lk[t2] > my) ? 1u : 0u;
        }
    }
    if (ci < nc) {
        unsigned int o = 0xFFFFFFFFu - (unsigned int)my;   // original index
        rank[o] = cnt;                                     // global sorted pos
        float4 b = ((const float4*)det_boxes)[o];          // [y1,x1,y2,x2]
        sbox[cnt] = b;
        sarea[cnt] = (b.w - b.y) * (b.z - b.x);            // (x2-x1)*(y2-y1)
    }
}

// Upper-triangular (block-wise) IoU>0.6 bit matrix, candidate chunks only.
// Persistent-tile kernel, fixed 1024-block grid.
__global__ void k_mask(const float4* __restrict__ sbox,
                       const float* __restrict__ sarea,
                       const int* __restrict__ ticket,
                       unsigned long long* __restrict__ mask) {
    int ncand = *ticket;
    if (ncand < 0) ncand = 0;
    if (ncand > N) ncand = N;
    int NC = (ncand + 63) >> 6;
    int total = NC * (NC + 1) / 2;
    __shared__ float4 cbox[64];
    __shared__ float carea[64];
    int t = threadIdx.x;
    for (int tile = blockIdx.x; tile < total; tile += gridDim.x) {
        int cb = (int)((sqrtf(8.0f * (float)tile + 1.0f) - 1.0f) * 0.5f);
        while ((cb + 1) * (cb + 2) / 2 <= tile) ++cb;
        while (cb * (cb + 1) / 2 > tile) --cb;
        int rb = tile - cb * (cb + 1) / 2;

        __syncthreads();                       // protect cbox reuse
        int col0 = cb * 64;
        cbox[t] = sbox[col0 + t];
        carea[t] = sarea[col0 + t];
        __syncthreads();
        int row = rb * 64 + t;
        float4 r = sbox[row];
        float ra = sarea[row];
        unsigned long long bits = 0ull;
        for (int j = 0; j < 64; ++j) {
            int col = col0 + j;
            if (col > row) {
                float4 cbx = cbox[j];
                float iw = fminf(r.w, cbx.w) - fmaxf(r.y, cbx.y);  // x overlap
                iw = fmaxf(iw, 0.0f);
                float ih = fminf(r.z, cbx.z) - fmaxf(r.x, cbx.x);  // y overlap
                ih = fmaxf(ih, 0.0f);
                float inter = iw * ih;
                float iou = inter / (ra + carea[j] - inter + 1e-12f);
                if (iou > 0.6f) bits |= (1ull << j);
            }
        }
        mask[(size_t)row * NWORDS + cb] = bits;
    }
}

// Serial greedy scan (lazy-gather) + ZERO-ROW SHORTCUT in phase A.
__global__ void __launch_bounds__(64, 1)
k_scan(const unsigned long long* __restrict__ mask,
       const int* __restrict__ ticket,
       unsigned long long* __restrict__ keepw_ws) {
    __shared__ unsigned long long keepw_arr[NWORDS];
    __shared__ int keptList[1024];
    int lane = threadIdx.x;
    for (int i2 = lane; i2 < NWORDS; i2 += 64) keepw_arr[i2] = 0ull;

    int ncand = *ticket;
    if (ncand < 0) ncand = 0;
    if (ncand > N) ncand = N;
    int NC = (ncand + 63) >> 6;

    int cnt = 0, nk = 0;
    unsigned long long dnext = 0ull;
    if (NC > 0) dnext = mask[(size_t)lane * NWORDS];   // chunk 0 diag word

    for (int c = 0; c < NC; ++c) {
        if (cnt >= MAX_DETS) break;                    // keepw_arr pre-zeroed

        unsigned long long dcur = dnext;               // row lane's diag word
        if (c + 1 < NC)                                // one-ahead prefetch
            dnext = mask[(size_t)((c + 1) * 64 + lane) * NWORDS + (c + 1)];
        unsigned int dlo = (unsigned int)dcur;
        unsigned int dhi = (unsigned int)(dcur >> 32);

        // lazy suppression gather: supp_c = OR over kept t of mask[t][c]
        unsigned long long acc = 0ull;
        {
            int q = lane;
            while (q < nk) {
#define GS(i)                                                             \
                unsigned long long G##i = 0ull;                           \
                {                                                         \
                    int qq = q + 64 * i;                                  \
                    if (qq < nk) {                                        \
                        int t = keptList[qq];                             \
                        G##i = mask[(size_t)t * NWORDS + c];              \
                    }                                                     \
                }
                GS(0) GS(1) GS(2) GS(3) GS(4) GS(5) GS(6) GS(7)
#undef GS
                acc |= G0 | G1 | G2 | G3 | G4 | G5 | G6 | G7;
                q += 512;
            }
        }
        unsigned int alo = (unsigned int)acc;
        unsigned int ahi = (unsigned int)(acc >> 32);
        for (int off = 32; off > 0; off >>= 1) {
            alo |= (unsigned int)__shfl_xor((int)alo, off, 64);
            ahi |= (unsigned int)__shfl_xor((int)ahi, off, 64);
        }
        unsigned long long sw =
            ((unsigned long long)(unsigned int)__builtin_amdgcn_readfirstlane(
                 (int)ahi) << 32) |
             (unsigned long long)(unsigned int)__builtin_amdgcn_readfirstlane(
                 (int)alo);
        unsigned long long alive = ~sw;
        if (ncand - c * 64 < 64)                       // clamp tail chunk
            alive &= ((1ull << (ncand - c * 64)) - 1ull);

        // zb: rows whose in-chunk suppression word is zero (can't affect alive)
        unsigned long long zb = __ballot(dcur == 0ull);

        // ---- phase A with zero-row shortcut ----
        unsigned long long keepw = 0ull;
        unsigned long long NZ = alive & ~zb;           // rows needing serial link
        while (true) {
            // segment of alive zero-rows before the next non-zero row
            unsigned long long below;
            int t = -1;
            if (NZ) { t = __ffsll((long long)NZ) - 1; below = (1ull << t) - 1ull; }
            else below = ~0ull;
            unsigned long long seg = alive & below;    // all zero-rows (kept)
            int segc = (int)__popcll(seg);
            if (cnt + segc >= MAX_DETS) {              // truncate inside segment
                int allow = MAX_DETS - cnt;
                unsigned long long r = 0ull;
                for (int k2 = 0; k2 < allow; ++k2) {
                    unsigned long long b = seg & (~seg + 1ull);
                    r |= b; seg ^= b;
                }
                keepw |= r; cnt = MAX_DETS; break;
            }
            keepw |= seg; cnt += segc; alive &= ~seg;
            if (t < 0) break;                          // no non-zero rows left
            // serial link for non-zero row t (t is alive: NZ subset of alive)
            keepw |= (1ull << t); ++cnt;
            if (cnt >= MAX_DETS) break;
            unsigned long long dt =
                ((unsigned long long)(unsigned int)__builtin_amdgcn_readlane(
                     (int)dhi, t) << 32) |
                 (unsigned long long)(unsigned int)__builtin_amdgcn_readlane(
                     (int)dlo, t);
            alive &= ~(dt | (1ull << t));
            NZ &= alive;                               // drop suppressed + t
            NZ &= ~(1ull << t);
        }
        if (lane == 0) keepw_arr[c] = keepw;

        // append kept positions to keptList (lane-parallel)
        if (keepw != 0ull) {
            if ((keepw >> lane) & 1ull) {
                int pre = (int)__popcll(keepw & ((1ull << lane) - 1ull));
                keptList[nk + pre] = c * 64 + lane;
            }
            nk += (int)__popcll(keepw);
        }
    }

    // write keep bits to ws (coalesced, 4 words/lane)
    for (int i2 = lane; i2 < NWORDS; i2 += 64) keepw_ws[i2] = keepw_arr[i2];
}

// Parallel valid bits: 64 blocks x 256. validw[w] bit j = valid(item w*64+j).
__global__ void k_valid(const unsigned long long* __restrict__ keepw_ws,
                        const unsigned int* __restrict__ rank,
                        const float* __restrict__ roi_boxes,
                        const float* __restrict__ roi_scores,
                        const float* __restrict__ det_boxes,
                        const float* __restrict__ info,
                        unsigned long long* __restrict__ validw) {
    int i = blockIdx.x * 256 + threadIdx.x;
    float sy = info[4], sx = info[5];
    unsigned int r = rank[i];
    bool keep = ((keepw_ws[(r >> 6) & (NWORDS - 1)] >> (r & 63)) & 1ull) != 0ull;
    float4 rb = ((const float4*)roi_boxes)[i];
    bool nz = !((rb.x == 0.0f) && (rb.y == 0.0f) && (rb.z == 0.0f) && (rb.w == 0.0f));
    bool sc = roi_scores[i] >= 0.9f;
    float4 db = ((const float4*)det_boxes)[i];
    float r0 = db.x / sy, r1 = db.y / sx, r2 = db.z / sy, r3 = db.w / sx;
    bool big = ((r2 - r0) * (r3 - r1)) > 220.0f;
    bool valid = keep && nz && sc && big;
    unsigned long long bal = __ballot(valid);
    if ((threadIdx.x & 63) == 0) validw[i >> 6] = bal;
}

// First-K pick from the valid bitmask: wave 0 (tids 0..63), lane l owns
// words l*4..l*4+3 (= items [l*256, l*256+256), order-preserving).
__device__ __forceinline__ void pick_first_k(
        const unsigned long long* __restrict__ validw,
        int* idxL, int* cntL, int tid) {
    if (tid < K) idxL[tid] = 0;          // fill_value = 0
    __syncthreads();
    if (tid < 64) {
        int lane = tid;
        unsigned long long w0 = validw[lane * 4 + 0];
        unsigned long long w1 = validw[lane * 4 + 1];
        unsigned long long w2 = validw[lane * 4 + 2];
        unsigned long long w3 = validw[lane * 4 + 3];
        int s = (int)(__popcll(w0) + __popcll(w1) + __popcll(w2) + __popcll(w3));
        int pref = s;                                  // inclusive prefix
        for (int off = 1; off < 64; off <<= 1) {
            int v = __shfl_up(pref, off, 64);
            if (lane >= off) pref += v;
        }
        int excl = pref - s;
        int total = __shfl(pref, 63, 64);
        if (lane == 0) *cntL = total;
        if (excl < K) {
            unsigned long long wsv[4] = { w0, w1, w2, w3 };
            int rk = excl;
            for (int q = 0; q < 4; ++q) {
                unsigned long long ww = wsv[q];
                while (ww && rk < K) {
                    int j = __ffsll((long long)ww) - 1;
                    ww &= ww - 1ull;
                    idxL[rk++] = (lane * 4 + q) * 64 + j;
                }
            }
        }
    }
    __syncthreads();
}

// Classification: one block per detection row. Same sequential accumulation
// order as the previously-passing fused version (absmax == 0 preserved).
__global__ void k_gemm(const unsigned long long* __restrict__ validw,
                       const float* __restrict__ vis,
                       const float* __restrict__ tf,
                       float* __restrict__ scoresW) {
    __shared__ int idxL[K];
    __shared__ int cntL;
    __shared__ float featL[FEAT];
    int tid = threadIdx.x;
    pick_first_k(validw, idxL, &cntL, tid);
    int o = idxL[blockIdx.x];
    if (tid < 128)
        ((float4*)featL)[tid] = ((const float4*)(vis + (size_t)o * FEAT))[tid];
    __syncthreads();
    if (tid < NUM_CATS) {
        const float* tr = &tf[(size_t)tid * FEAT];
        float s = 0.0f;
#pragma unroll 8
        for (int e = 0; e < FEAT; ++e) s += featL[e] * tr[e];
        scoresW[blockIdx.x * NUM_CATS + tid] = s;
    }
}

// Final: argmax/fg, stable descending sort, epilogue writes.
__global__ void k_final(const unsigned long long* __restrict__ validw,
                        const float* __restrict__ scoresW,
                        const float* __restrict__ det_boxes,
                        const float* __restrict__ info,
                        float* __restrict__ out) {
    __shared__ int idxL[K];
    __shared__ int cntL;
    __shared__ float scL[K * NUM_CATS];
    __shared__ float keyL[K];
    __shared__ int fgL[K];
    __shared__ int ordL[K];
    int tid = threadIdx.x;
    pick_first_k(validw, idxL, &cntL, tid);

    for (int p = tid; p < K * NUM_CATS; p += 256) scL[p] = scoresW[p];
    __syncthreads();

    int count = cntL;
    int mincount = count < K ? count : K;

    if (tid < K) {
        float mv = scL[tid * NUM_CATS];
        int ma = 0;
        for (int c = 1; c < NUM_CATS; ++c) {
            float v = scL[tid * NUM_CATS + c];
            if (v > mv) { mv = v; ma = c; }     // first-max (jnp.argmax)
        }
        int fg = (tid < mincount) && (ma != 0);
        fgL[tid] = fg;
        keyL[tid] = fg ? mv : -INFINITY;
    }
    __syncthreads();

    if (tid == 0) {                 // stable selection sort, descending
        unsigned used = 0;
        for (int p = 0; p < K; ++p) {
            int bk = -1; float bv = 0.0f;
            for (int k2 = 0; k2 < K; ++k2) {
                if (used & (1u << k2)) continue;
                if (bk < 0 || keyL[k2] > bv) { bk = k2; bv = keyL[k2]; }
            }
            ordL[p] = bk;
            used |= (1u << bk);
        }
    }
    __syncthreads();

    float sy = info[4], sx = info[5];
    // scores: [0 .. 1599]
    for (int p = tid; p < K * (NUM_CATS - 1); p += 256) {
        int q = p >> 6, cc = p & 63;
        int src = ordL[q];
        out[p] = fgL[src] ? scL[src * NUM_CATS + cc + 1] : 0.0f;
    }
    // bboxes: [1600 .. 1699]  processed = [xmin, ymin, xmax, ymax]
    for (int p = tid; p < K * 4; p += 256) {
        int q = p >> 2, e = p & 3;
        int src = ordL[q];
        float v = 0.0f;
        if (fgL[src]) {
            int o = idxL[src];
            float b0 = det_boxes[o * 4 + 0] / sy;   // ymin
            float b1 = det_boxes[o * 4 + 1] / sx;   // xmin
            float b2 = det_boxes[o * 4 + 2] / sy;   // ymax
            float b3 = det_boxes[o * 4 + 3] / sx;   // xmax
            v = (e == 0) ? b1 : (e == 1) ? b0 : (e == 2) ? b3 : b2;
        }
        out[1600 + p] = v;
    }
    // mask: [1700 .. 1724]
    if (tid < K) out[1700 + tid] = fgL[ordL[tid]] ? 1.0f : 0.0f;
}

extern "C" void kernel_launch(void* const* d_in, const int* in_sizes, int n_in,
                              void* d_out, int out_size, void* d_ws, size_t ws_size,
                              hipStream_t stream) {
    const float* roi_boxes  = (const float*)d_in[0];
    const float* roi_scores = (const float*)d_in[1];
    const float* det_boxes  = (const float*)d_in[2];
    // d_in[3] detection_masks: unused by reference
    const float* vis        = (const float*)d_in[4];
    const float* info       = (const float*)d_in[5];
    const float* tf         = (const float*)d_in[6];

    char* ws = (char*)d_ws;
    unsigned long long* ckeys = (unsigned long long*)(ws + 0);
    unsigned int* rank        = (unsigned int*)(ws + 131072);
    float4* sbox              = (float4*)(ws + 262144);
    float* sarea              = (float*)(ws + 524288);
    unsigned long long* mask  = (unsigned long long*)(ws + 589824);
    int* idxArr               = (int*)(ws + 34144256);
    unsigned long long* keepw = (unsigned long long*)(ws + 34144384);
    unsigned long long* validw= (unsigned long long*)(ws + 34146432);
    float* scoresW            = (float*)(ws + 34148480);
    int* ticket               = idxArr + 30;

    hipMemsetAsync(idxArr, 0, 128, stream);   // zero ticket (graph-capture safe)
    k_build<<<64, 256, 0, stream>>>(roi_scores, ckeys, rank, ticket);
    k_crank<<<64, 256, 0, stream>>>(ckeys, ticket, det_boxes, rank, sbox, sarea);
    k_mask<<<1024, 64, 0, stream>>>(sbox, sarea, ticket, mask);
    k_scan<<<1, 64, 0, stream>>>(mask, ticket, keepw);
    k_valid<<<64, 256, 0, stream>>>(keepw, rank, roi_boxes, roi_scores,
                                    det_boxes, info, validw);
    k_gemm<<<K, 256, 0, stream>>>(validw, vis, tf, scoresW);
    k_final<<<1, 256, 0, stream>>>(validw, scoresW, det_boxes, info, (float*)d_out);
}